// Round 8
// baseline (146.214 us; speedup 1.0000x reference)
//
#include <hip/hip_runtime.h>
#include <math.h>

#define NPTS 4096
#define BLK 256
#define PAIR_BLOCKS 4096
#define EV_BLOCKS 1024
#define TOTAL_BLOCKS (PAIR_BLOCKS + EV_BLOCKS)   // 5120; every 5th block is an ev block
#define VB 4                                     // ILP batch width
#define CNT_OFF (TOTAL_BLOCKS * 4)               // byte offset of counter in d_ws
#define NLOG2E (-1.4426950408889634f)

// ---------------- block-level float reduction (deterministic; result in thread 0) ----
__device__ __forceinline__ float block_reduce_f(float v) {
    #pragma unroll
    for (int off = 32; off > 0; off >>= 1)
        v += __shfl_down(v, off, 64);
    __shared__ float smem[BLK / 64];
    const int lane = threadIdx.x & 63;
    const int wid  = threadIdx.x >> 6;
    if (lane == 0) smem[wid] = v;
    __syncthreads();
    float t = 0.f;
    if (threadIdx.x == 0) {
        #pragma unroll
        for (int w = 0; w < BLK / 64; ++w) t += smem[w];
    }
    return t;
}

// ---------------- fused kernel: pair integral + event intensity; last block combines --
__global__ __launch_bounds__(BLK, 8) void fused_kernel(
        const int* __restrict__ eu, const int* __restrict__ ev,
        const float* __restrict__ et,
        const float2* __restrict__ z0, const float2* __restrict__ v0,
        const float* __restrict__ beta_p, const float* __restrict__ t0_p,
        const float* __restrict__ tn_p,
        float* __restrict__ partial, unsigned* __restrict__ cnt,
        float* __restrict__ out, int nE) {
    const int bid = blockIdx.x;
    const float b = beta_p[0];
    float acc = 0.f;

    if (bid % 5 == 0) {
        // ----- event part: sum_e ||dz + dv*t||^2 ; batched prefetch of 4 iters -----
        const int ev_id = bid / 5;                       // [0, EV_BLOCKS)
        const int base  = ev_id * BLK + threadIdx.x;
        int   u[4], w[4];
        float t[4];
        bool  act[4];
        #pragma unroll
        for (int k = 0; k < 4; ++k) {
            const int idx = base + k * (EV_BLOCKS * BLK);   // 4*262144 >= 1e6
            act[k] = (idx < nE);
            const int safe = act[k] ? idx : 0;
            u[k] = eu[safe]; w[k] = ev[safe]; t[k] = et[safe];
        }
        float2 zu[4], zw[4], vu[4], vw[4];
        #pragma unroll
        for (int k = 0; k < 4; ++k) {
            zu[k] = z0[u[k]]; zw[k] = z0[w[k]];
            vu[k] = v0[u[k]]; vw[k] = v0[w[k]];
        }
        #pragma unroll
        for (int k = 0; k < 4; ++k) {
            const float dx = fmaf(vu[k].x - vw[k].x, t[k], zu[k].x - zw[k].x);
            const float dy = fmaf(vu[k].y - vw[k].y, t[k], zu[k].y - zw[k].y);
            const float d2 = fmaf(dx, dx, dy * dy);
            acc += act[k] ? d2 : 0.f;
        }
    } else {
        // ----- pair part: each unordered pair exactly once; V=4 stage-batched ILP ----
        const int pair_id = bid - (bid / 5 + 1);         // [0, PAIR_BLOCKS)
        const float t0 = t0_p[0];
        const float tn = tn_p[0];
        const float C  = -0.88622692545275801365f * __expf(b);   // -sqrt(pi)/2 * e^b

        const int tid0 = pair_id * BLK + threadIdx.x;    // idx for it=0; stride 2^20 per it
        const int j    = tid0 & (NPTS - 1);              // fixed per thread
        const int i0   = tid0 >> 12;                     // [0, 256); i = i0 + it*256
        const int jf   = NPTS - 1 - j;
        const float2 zj  = z0[j],  vj  = v0[j];
        const float2 zjf = z0[jf], vjf = v0[jf];

        #pragma unroll
        for (int half = 0; half < 2; ++half) {
            // ---- stage 1: coords, loads, operand assembly (4 independent cells) ----
            float a[VB], bbv[VB], m[VB], n[VB];
            bool  ok[VB];
            #pragma unroll
            for (int k = 0; k < VB; ++k) {
                const int it = half * VB + k;
                const int i  = i0 + it * 256;            // block-uniform value
                const bool fold = (j < i);               // per-lane
                ok[k] = (j != i);
                const int ii = fold ? (NPTS - 1 - i) : i;
                const float2 zi = z0[ii];
                const float2 vi = v0[ii];
                a[k]   = zi.x - (fold ? zjf.x : zj.x);
                bbv[k] = zi.y - (fold ? zjf.y : zj.y);
                m[k]   = vi.x - (fold ? vjf.x : vj.x);
                n[k]   = vi.y - (fold ? vjf.y : vj.y);
            }
            // ---- stage 2: batched algebra ----
            float s2[VB], inv_s[VB], am[VB], q[VB];
            #pragma unroll
            for (int k = 0; k < VB; ++k) s2[k] = fmaf(m[k], m[k], n[k] * n[k]);
            #pragma unroll
            for (int k = 0; k < VB; ++k) inv_s[k] = __builtin_amdgcn_rsqf(s2[k]);
            #pragma unroll
            for (int k = 0; k < VB; ++k) am[k] = fmaf(a[k], m[k], bbv[k] * n[k]);
            #pragma unroll
            for (int k = 0; k < VB; ++k) q[k] = fmaf(bbv[k], m[k], -a[k] * n[k]) * inv_s[k];
            // ---- stage 3: batched erf args ----
            float x1[VB], x2[VB];
            #pragma unroll
            for (int k = 0; k < VB; ++k) x1[k] = fmaf(s2[k], t0, am[k]) * inv_s[k];
            #pragma unroll
            for (int k = 0; k < VB; ++k) x2[k] = fmaf(s2[k], tn, am[k]) * inv_s[k];
            // ---- stage 4: batched 3-term A&S 7.1.25 erf (|err|<=2.5e-5) ----
            float t1[VB], t2[VB], g1[VB], g2[VB];
            #pragma unroll
            for (int k = 0; k < VB; ++k) t1[k] = __builtin_amdgcn_rcpf(fmaf(0.47047f, fabsf(x1[k]), 1.0f));
            #pragma unroll
            for (int k = 0; k < VB; ++k) t2[k] = __builtin_amdgcn_rcpf(fmaf(0.47047f, fabsf(x2[k]), 1.0f));
            #pragma unroll
            for (int k = 0; k < VB; ++k) g1[k] = exp2f((x1[k] * x1[k]) * NLOG2E);
            #pragma unroll
            for (int k = 0; k < VB; ++k) g2[k] = exp2f((x2[k] * x2[k]) * NLOG2E);
            float e1[VB], e2[VB];
            #pragma unroll
            for (int k = 0; k < VB; ++k) {
                float p = fmaf(t1[k], 0.7478556f, -0.0958798f);
                p = fmaf(t1[k], p, 0.3480242f);
                p *= t1[k];
                e1[k] = copysignf(fmaf(-p, g1[k], 1.0f), x1[k]);
            }
            #pragma unroll
            for (int k = 0; k < VB; ++k) {
                float p = fmaf(t2[k], 0.7478556f, -0.0958798f);
                p = fmaf(t2[k], p, 0.3480242f);
                p *= t2[k];
                e2[k] = copysignf(fmaf(-p, g2[k], 1.0f), x2[k]);
            }
            // ---- stage 5: Gaussian factor + masked accumulate (select kills diag NaN) --
            float E[VB];
            #pragma unroll
            for (int k = 0; k < VB; ++k) E[k] = exp2f((q[k] * q[k]) * NLOG2E);
            #pragma unroll
            for (int k = 0; k < VB; ++k) {
                const float contrib = (C * E[k]) * (e1[k] - e2[k]) * inv_s[k];
                acc += ok[k] ? contrib : 0.f;
            }
        }
    }

    // ----- block reduce + last-block deterministic combine -----
    const float r = block_reduce_f(acc);
    __shared__ bool amLast;
    if (threadIdx.x == 0) {
        __hip_atomic_store(&partial[bid], r, __ATOMIC_RELEASE, __HIP_MEMORY_SCOPE_AGENT);
        const unsigned old = __hip_atomic_fetch_add(cnt, 1u, __ATOMIC_ACQ_REL,
                                                    __HIP_MEMORY_SCOPE_AGENT);
        amLast = (old == TOTAL_BLOCKS - 1);
    }
    __syncthreads();

    if (amLast) {
        __shared__ double sd[BLK];
        double s = 0.0;
        #pragma unroll
        for (int k = 0; k < TOTAL_BLOCKS / BLK; ++k)
            s += (double)__hip_atomic_load(&partial[threadIdx.x + k * BLK],
                                           __ATOMIC_RELAXED, __HIP_MEMORY_SCOPE_AGENT);
        sd[threadIdx.x] = s;
        __syncthreads();
        for (int st = BLK / 2; st > 0; st >>= 1) {
            if (threadIdx.x < st) sd[threadIdx.x] += sd[threadIdx.x + st];
            __syncthreads();
        }
        if (threadIdx.x == 0)
            out[0] = (float)((double)nE * (double)b - sd[0]);
    }
}

extern "C" void kernel_launch(void* const* d_in, const int* in_sizes, int n_in,
                              void* d_out, int out_size, void* d_ws, size_t ws_size,
                              hipStream_t stream) {
    const int*    eu   = (const int*)d_in[0];
    const int*    ev   = (const int*)d_in[1];
    const float*  et   = (const float*)d_in[2];
    const float*  t0   = (const float*)d_in[3];
    const float*  tn   = (const float*)d_in[4];
    const float*  beta = (const float*)d_in[5];
    const float2* z0   = (const float2*)d_in[6];
    const float2* v0   = (const float2*)d_in[7];
    float* out = (float*)d_out;
    const int nE = in_sizes[0];

    float*    partial = (float*)d_ws;                      // TOTAL_BLOCKS floats
    unsigned* cnt     = (unsigned*)((char*)d_ws + CNT_OFF);

    hipMemsetAsync((void*)cnt, 0, sizeof(unsigned), stream);
    fused_kernel<<<TOTAL_BLOCKS, BLK, 0, stream>>>(eu, ev, et, z0, v0, beta, t0, tn,
                                                   partial, cnt, out, nE);
}